// Round 11
// baseline (394.700 us; speedup 1.0000x reference)
//
#include <hip/hip_runtime.h>
#include <stdint.h>

typedef __bf16 bf16;
typedef __bf16 bf16x8 __attribute__((ext_vector_type(8)));
typedef float floatx4 __attribute__((ext_vector_type(4)));
typedef float floatx16 __attribute__((ext_vector_type(16)));

#define HH     16
#define DNOPE  128
#define DROPE  64
#define DV     128
#define DQK    192
#define HID    2048
#define QLR    1536
#define KVLR   512
#define BB     4
#define SS     1024
#define NTOK   4096
#define XOUTW  2176
#define EPSF   1e-6f

// ---------------- helpers ----------------
__device__ inline void cvt_store4(bf16* dst, float a, float b, float c, float d) {
  union { bf16 h[4]; uint2 u; } t;
  t.h[0] = (bf16)a; t.h[1] = (bf16)b; t.h[2] = (bf16)c; t.h[3] = (bf16)d;
  *(uint2*)dst = t.u;
}

__device__ inline void gl_lds16(const bf16* g, bf16* l) {
  __builtin_amdgcn_global_load_lds(
      (const __attribute__((address_space(1))) void*)g,
      (__attribute__((address_space(3))) void*)l, 16, 0, 0);
}

// ---------------- merged fp32 -> bf16 conversion (all weights + x) --------
__global__ __launch_bounds__(256) void cvt_all(
    const float* __restrict__ x, const float* __restrict__ wq_a,
    const float* __restrict__ wkv_a, const float* __restrict__ wq_b,
    const float* __restrict__ wk_b, const float* __restrict__ wv_b,
    const float* __restrict__ wo, bf16* __restrict__ xb,
    bf16* __restrict__ wA, bf16* __restrict__ wqbb,
    bf16* __restrict__ wkvB, bf16* __restrict__ wob, float scaleq) {
  const int blk = blockIdx.x, tid = threadIdx.x;
  const float* s; bf16* d; int rel; float sc = 1.0f;
  if (blk < 8192)       { rel = blk;         s = x;    d = xb; }
  else if (blk < 11264) { rel = blk - 8192;  s = wq_a; d = wA; }
  else if (blk < 12544) { // wkv_a pad to 640 rows
    rel = blk - 11264;
    int i = (rel * 256 + tid) << 2;
    bf16* dd = wA + 3145728;
    if ((i >> 11) < 576) {
      float4 v = *(const float4*)(wkv_a + i);
      cvt_store4(dd + i, v.x, v.y, v.z, v.w);
    } else {
      *(uint2*)(dd + i) = make_uint2(0u, 0u);
    }
    return;
  }
  else if (blk < 17152) { rel = blk - 12544; s = wq_b; d = wqbb; sc = scaleq; }
  else if (blk < 18176) { rel = blk - 17152; s = wk_b; d = wkvB; }
  else if (blk < 19200) { rel = blk - 18176; s = wv_b; d = wkvB + 1048576; }
  else                  { rel = blk - 19200; s = wo;   d = wob; }
  int i = (rel * 256 + tid) << 2;
  float4 v = *(const float4*)(s + i);
  cvt_store4(d + i, v.x * sc, v.y * sc, v.z * sc, v.w * sc);
}

// ---------------- GEMM: C[M,N] = A[M,K] @ Bw[N,K]^T (all bf16 in) ----------
// Proven R6/R8 config: 128^2 tile, BK=32, THREE 16KB stages (48KB LDS ->
// 3 blocks/CU), counted depth-2 pipeline (wait vmcnt(4); barrier; issue
// k+2; compute k), T2 swizzle (pre-swizzled global source + XOR'd read),
// XCD block swizzle. ~620-660 TF -- at the counted-2-phase ceiling.
// EPI: 0 = plain store, 1 = dual knope/vT epilogue, 2 = fused rope-q.
template <typename TC, int EPI>
__global__ __launch_bounds__(256) void gemm_bt_bf16(
    const bf16* __restrict__ A, const bf16* __restrict__ Bw,
    TC* __restrict__ C0, bf16* __restrict__ C1, int M, int N, int K,
    const float* __restrict__ rs, const float* __restrict__ rc) {
  __shared__ __align__(16) bf16 As[3][128 * 32];
  __shared__ __align__(16) bf16 Bs[3][128 * 32];
  const int tid  = threadIdx.x;
  const int wave = tid >> 6, lane = tid & 63;
  const int gx = gridDim.x;
  const int fid = blockIdx.y * gx + blockIdx.x;
  const int cpx = (gx * gridDim.y) >> 3;
  const int sid = (fid & 7) * cpx + (fid >> 3);
  const int m0 = (sid % gx) << 7, n0 = (sid / gx) << 7;
  const int quad = lane >> 4, l16 = lane & 15;
  const int wm = (wave >> 1) << 6, wn = (wave & 1) << 6;

  const int srow0 = tid >> 2, g = tid & 3;
  const int gsw = g ^ ((srow0 >> 1) & 3);
  const int d0 = srow0 * 32 + (g << 3);
  const int d1 = d0 + 64 * 32;
  const bf16* gA0 = A  + (size_t)(m0 + srow0) * K + (gsw << 3);
  const bf16* gA1 = A  + (size_t)(m0 + srow0 + 64) * K + (gsw << 3);
  const bf16* gB0 = Bw + (size_t)(n0 + srow0) * K + (gsw << 3);
  const bf16* gB1 = Bw + (size_t)(n0 + srow0 + 64) * K + (gsw << 3);

  floatx4 acc[4][4];
#pragma unroll
  for (int i = 0; i < 4; i++)
#pragma unroll
    for (int j = 0; j < 4; j++) acc[i][j] = floatx4{0.f, 0.f, 0.f, 0.f};

  const int nk = K >> 5;
  gl_lds16(gA0, As[0] + d0); gl_lds16(gA1, As[0] + d1);
  gl_lds16(gB0, Bs[0] + d0); gl_lds16(gB1, Bs[0] + d1);
  gl_lds16(gA0 + 32, As[1] + d0); gl_lds16(gA1 + 32, As[1] + d1);
  gl_lds16(gB0 + 32, Bs[1] + d0); gl_lds16(gB1 + 32, Bs[1] + d1);

  const int swr = (l16 >> 1) & 3;
  int cur = 0, nx2 = 2;
  for (int kt = 0; kt < nk; kt++) {
    if (kt + 1 < nk)
      asm volatile("s_waitcnt vmcnt(4)\n\ts_barrier" ::: "memory");
    else
      asm volatile("s_waitcnt vmcnt(0)\n\ts_barrier" ::: "memory");
    if (kt + 2 < nk) {
      const size_t kk = (size_t)(kt + 2) << 5;
      gl_lds16(gA0 + kk, As[nx2] + d0); gl_lds16(gA1 + kk, As[nx2] + d1);
      gl_lds16(gB0 + kk, Bs[nx2] + d0); gl_lds16(gB1 + kk, Bs[nx2] + d1);
    }
    __builtin_amdgcn_sched_barrier(0);   // pin DMA issue before compute

    const bf16* cA = As[cur];
    const bf16* cB = Bs[cur];
    bf16x8 af[4], bv[4];
#pragma unroll
    for (int i = 0; i < 4; i++) {
      const int r = wm + (i << 4) + l16;
      af[i] = *(const bf16x8*)&cA[r * 32 + (((quad ^ swr) & 3) << 3)];
    }
#pragma unroll
    for (int j = 0; j < 4; j++) {
      const int r = wn + (j << 4) + l16;
      bv[j] = *(const bf16x8*)&cB[r * 32 + (((quad ^ swr) & 3) << 3)];
    }
#pragma unroll
    for (int i = 0; i < 4; i++)
#pragma unroll
      for (int j = 0; j < 4; j++)
        acc[i][j] = __builtin_amdgcn_mfma_f32_16x16x32_bf16(af[i], bv[j], acc[i][j], 0, 0, 0);

    cur = (cur == 2) ? 0 : cur + 1;
    nx2 = (nx2 == 2) ? 0 : nx2 + 1;
  }

  if constexpr (EPI == 1) {
    if (n0 >= 2048) {
#pragma unroll
      for (int i = 0; i < 4; i++) {
        int gm = m0 + wm + (i << 4) + (quad << 2);
        int bb = gm >> 10, s = gm & 1023;
#pragma unroll
        for (int j = 0; j < 4; j++) {
          int gn = n0 + wn + (j << 4) + l16 - 2048;
          int hh = gn >> 7, vd = gn & 127;
          union { bf16 h4[4]; uint2 u; } pk;
#pragma unroll
          for (int r = 0; r < 4; r++) pk.h4[r] = (bf16)acc[i][j][r];
          *(uint2*)(C1 + ((((size_t)bb * HH + hh) * DV + vd) << 10) + s) = pk.u;
        }
      }
      return;
    }
  }
  if constexpr (EPI == 2) {
    // fused rope-q: rotate pairs where head-local d = (col%192) in [128,192)
#pragma unroll
    for (int i = 0; i < 4; i++)
#pragma unroll
      for (int j = 0; j < 4; j++) {
        const int cb = (n0 + wn + (j << 4)) % 192;   // j-tile head-local base
        const int gn = n0 + wn + (j << 4) + l16;
        if (cb >= 128) {                              // wave-uniform branch
          const int ir = (cb + l16 - 128) >> 1;       // same for both pair lanes
#pragma unroll
          for (int r = 0; r < 4; r++) {
            int gm = m0 + wm + (i << 4) + (quad << 2) + r;
            int pos = gm & (SS - 1);
            float own  = acc[i][j][r];
            float part = __shfl_xor(own, 1);          // pair partner (lane^1)
            float cth = rc[(pos << 5) + ir], sth = rs[(pos << 5) + ir];
            acc[i][j][r] = (l16 & 1) ? (part * sth + own * cth)   // odd:  o'
                                     : (own * cth - part * sth);  // even: e'
          }
        }
#pragma unroll
        for (int r = 0; r < 4; r++) {
          int gm = m0 + wm + (i << 4) + (quad << 2) + r;
          C0[(size_t)gm * N + gn] = (TC)acc[i][j][r];
        }
      }
    return;
  }
  const int ldc = (EPI == 1) ? 2048 : N;
#pragma unroll
  for (int i = 0; i < 4; i++)
#pragma unroll
    for (int j = 0; j < 4; j++) {
      int gn = n0 + wn + (j << 4) + l16;
#pragma unroll
      for (int r = 0; r < 4; r++) {
        int gm = m0 + wm + (i << 4) + (quad << 2) + r;
        C0[(size_t)gm * ldc + gn] = (TC)acc[i][j][r];
      }
    }
}

// ---------------- fused rmsnorm(q) + rmsnorm(kv) + rope_k ----------------
__global__ __launch_bounds__(256) void norm_rope(
    const bf16* __restrict__ xout, const float* __restrict__ w_qa_ln,
    const float* __restrict__ w_kva_ln, bf16* __restrict__ qln,
    bf16* __restrict__ ckv, bf16* __restrict__ kpe,
    const float* __restrict__ rsin, const float* __restrict__ rcos) {
  const int blk = blockIdx.x, tid = threadIdx.x;
  if (blk < 8192) {
    const int row = blk & 4095;
    const bool isq = blk < 4096;
    const bf16* p = xout + (size_t)row * XOUTW + (isq ? 0 : QLR);
    const float* w = isq ? w_qa_ln : w_kva_ln;
    bf16* o = isq ? (qln + (size_t)row * QLR) : (ckv + (size_t)row * KVLR);
    const int L = isq ? QLR : KVLR;
    float ss = 0.f;
    for (int c = tid << 2; c < L; c += 1024) {
      union { uint2 u; bf16 h[4]; } t;
      t.u = *(const uint2*)(p + c);
#pragma unroll
      for (int r = 0; r < 4; r++) { float v = (float)t.h[r]; ss += v * v; }
    }
#pragma unroll
    for (int off = 32; off > 0; off >>= 1) ss += __shfl_down(ss, off);
    __shared__ float red[4];
    if ((tid & 63) == 0) red[tid >> 6] = ss;
    __syncthreads();
    float rs = rsqrtf((red[0] + red[1] + red[2] + red[3]) / (float)L + EPSF);
    for (int c = tid << 2; c < L; c += 1024) {
      union { uint2 u; bf16 h[4]; } t, ot;
      t.u = *(const uint2*)(p + c);
#pragma unroll
      for (int r = 0; r < 4; r++) ot.h[r] = (bf16)((float)t.h[r] * rs * w[c + r]);
      *(uint2*)(o + c) = ot.u;
    }
  } else {
    int idx = (blk - 8192) * 256 + tid;   // NTOK*32
    int i = idx & 31, row = idx >> 5;
    int pos = row & (SS - 1);
    union { uint u; bf16 h2[2]; } t;
    t.u = *(const uint*)(xout + (size_t)row * XOUTW + QLR + KVLR + (i << 1));
    float e = (float)t.h2[0], o = (float)t.h2[1];
    float c = rcos[(pos << 5) + i], s = rsin[(pos << 5) + i];
    t.h2[0] = (bf16)(e * c - o * s);
    t.h2[1] = (bf16)(e * s + o * c);
    *(uint*)(kpe + (size_t)row * DROPE + (i << 1)) = t.u;
  }
}

// ---------------- flash attention: paired q-128 tiles, balanced blocks -----
// R8 config (best measured) + R11 change: 1D grid with XCD-GROUPED swizzle.
// FETCH_SIZE showed ~29MB of KV re-reads (ideal 58MB, measured 87MB): the
// 4 blocks sharing one (b,h)'s KV stream (bt=0..3, consecutive ids) were
// round-robined onto DIFFERENT XCDs -> each private L2 refetched the same
// KV slots, and every per-slot vmcnt(0) drain paid L3/HBM latency. Remap
// logical = (p&7)*32 + p/8 (bijective, 256 blocks): each XCD hosts 32
// consecutive logical blocks = 8 complete (b,h) groups -> 1 fetch + 3 L2
// hits per KV slot; working set ~1-2MB << 4MB L2. Kernel body unchanged.
__global__ __launch_bounds__(512, 2) void attn_kernel(
    const bf16* __restrict__ q, const bf16* __restrict__ knope,
    const bf16* __restrict__ kpe, const bf16* __restrict__ vT,
    bf16* __restrict__ out) {
  const int p = blockIdx.x;
  const int logical = ((p & 7) << 5) + (p >> 3);
  const int bt = logical & 3;          // 0..3 -> tile pair {bt, 7-bt}
  const int h = (logical >> 2) & 15, b = logical >> 6;
  const int nkt = (8 - bt) << 1;       // slots for the longer tile
  // per-20480-elem buffer: Kn [0,8192) Kp [8192,12288) Vt [12288,20480)
  __shared__ __align__(16) bf16 smem[40960];
  const int tid = threadIdx.x, wave = tid >> 6, lane = tid & 63;
  const int l32 = lane & 31, hi = lane >> 5;
  const int hi4 = hi << 2;
  const int tile = (wave < 4) ? bt : (7 - bt);
  const int Q0w = (tile << 7) + ((wave & 3) << 5);  // this wave's first q row
  const int qg = Q0w + l32;            // this lane's q row (col of S^T)

  // ---- per-lane global staging addresses (slot 0), swizzle inverse map ----
  const bf16 *gkn0, *gkn1, *gkp, *gvt0, *gvt1;
  {
    int c = wave << 1;
    int r = (c << 2) + (lane >> 4);
    int bi = (lane & 15) ^ (r & 15);
    gkn0 = knope + ((size_t)((b << 10) + r) * HH + h) * DNOPE + (bi << 3);
    r = ((c + 1) << 2) + (lane >> 4);
    bi = (lane & 15) ^ (r & 15);
    gkn1 = knope + ((size_t)((b << 10) + r) * HH + h) * DNOPE + (bi << 3);
    r = (wave << 3) + (lane >> 3);
    bi = (lane & 7) ^ (r & 7);
    gkp = kpe + (size_t)((b << 10) + r) * DROPE + (bi << 3);
    int dv = (wave << 4) + (lane >> 3);
    bi = (lane & 7) ^ (dv & 7);
    gvt0 = vT + ((((size_t)b * HH + h) * DV + dv) << 10) + (bi << 3);
    dv += 8;
    bi = (lane & 7) ^ (dv & 7);
    gvt1 = vT + ((((size_t)b * HH + h) * DV + dv) << 10) + (bi << 3);
  }
  const size_t knstep = (size_t)64 * HH * DNOPE;
  const size_t kpstep = (size_t)64 * DROPE;
  const int woff = wave << 10, woff2 = wave << 9;

  // issue slot-0 DMA into buf0
  gl_lds16(gkn0, smem + woff);
  gl_lds16(gkn1, smem + woff + 512);
  gl_lds16(gkp,  smem + 8192 + woff2);
  gl_lds16(gvt0, smem + 12288 + woff);
  gl_lds16(gvt1, smem + 12288 + woff + 512);
  gkn0 += knstep; gkn1 += knstep; gkp += kpstep; gvt0 += 64; gvt1 += 64;

  // ---- Q B-frags direct from global: B[n=q=l32][k=d], d = dc*16+hi*8+j ----
  bf16x8 qb[12];
  {
    const bf16* qbase =
        q + ((size_t)((b << 10) + Q0w + l32) * HH + h) * DQK + (hi << 3);
#pragma unroll
    for (int dc = 0; dc < 12; dc++)
      qb[dc] = *(const bf16x8*)(qbase + (dc << 4));
  }

  floatx16 acc[4];
#pragma unroll
  for (int g = 0; g < 4; g++)
#pragma unroll
    for (int r = 0; r < 16; r++) acc[g][r] = 0.f;
  float m_i = -1e30f, l_i = 0.f;

  for (int s = 0; s < nkt; s++) {
    const int k0 = s << 6;
    // slot-s DMA (+ prologue Q loads at s=0) drained per-wave, then barrier:
    // all waves have slot-s data; all waves done computing slot s-1.
    asm volatile("s_waitcnt vmcnt(0)\n\ts_barrier" ::: "memory");
    if (s + 1 < nkt) {   // issue slot s+1 into the other buffer
      bf16* bufp = smem + ((s + 1) & 1) * 20480;
      gl_lds16(gkn0, bufp + woff);
      gl_lds16(gkn1, bufp + woff + 512);
      gl_lds16(gkp,  bufp + 8192 + woff2);
      gl_lds16(gvt0, bufp + 12288 + woff);
      gl_lds16(gvt1, bufp + 12288 + woff + 512);
      gkn0 += knstep; gkn1 += knstep; gkp += kpstep; gvt0 += 64; gvt1 += 64;
    }
    __builtin_amdgcn_sched_barrier(0);   // pin DMA issue before compute
    if (k0 > Q0w + 31) continue;         // fully masked for this wave: skip

    const bf16* Kn = smem + (s & 1) * 20480;
    const bf16* Kp = Kn + 8192;
    const bf16* Vt = Kn + 12288;

    // ---- S^T = K @ Q^T : two 32x32 tiles (k-rows 0..31, 32..63) ----------
    floatx16 s0, s1;
#pragma unroll
    for (int r = 0; r < 16; r++) { s0[r] = 0.f; s1[r] = 0.f; }
    __builtin_amdgcn_s_setprio(1);
#pragma unroll
    for (int dc = 0; dc < 12; dc++) {
      bf16x8 ak0, ak1;
      if (dc < 8) {
        int gi = (((dc << 1) + hi) ^ (l32 & 15)) << 3;
        ak0 = *(const bf16x8*)&Kn[(l32 << 7) + gi];
        ak1 = *(const bf16x8*)&Kn[((32 + l32) << 7) + gi];
      } else {
        int gi = ((((dc - 8) << 1) + hi) ^ (l32 & 7)) << 3;
        ak0 = *(const bf16x8*)&Kp[(l32 << 6) + gi];
        ak1 = *(const bf16x8*)&Kp[((32 + l32) << 6) + gi];
      }
      s0 = __builtin_amdgcn_mfma_f32_32x32x16_bf16(ak0, qb[dc], s0, 0, 0, 0);
      s1 = __builtin_amdgcn_mfma_f32_32x32x16_bf16(ak1, qb[dc], s1, 0, 0, 0);
    }
    __builtin_amdgcn_s_setprio(0);

    // ---- causal mask (diagonal-region slots only, wave-uniform branch) ---
    if (k0 + 63 > Q0w) {
#pragma unroll
      for (int r = 0; r < 16; r++) {
        int rp = (r & 3) + ((r >> 2) << 3) + hi4;   // k row within tile
        if (k0 + rp > qg)      s0[r] = -1e30f;
        if (k0 + 32 + rp > qg) s1[r] = -1e30f;
      }
    }

    // ---- online softmax, fully in-register (lane owns q-col) -------------
    float mx = -1e30f;
#pragma unroll
    for (int r = 0; r < 16; r++) mx = fmaxf(mx, fmaxf(s0[r], s1[r]));
    mx = fmaxf(mx, __shfl_xor(mx, 32));   // lanes l,l^32 share the q-col
    if (!__all(mx - m_i <= 8.0f)) {       // defer-max (T13, THR=8)
      float mnew = fmaxf(m_i, mx);
      float alpha = exp2f(m_i - mnew);
      l_i *= alpha;
#pragma unroll
      for (int g = 0; g < 4; g++)
#pragma unroll
        for (int r = 0; r < 16; r++) acc[g][r] *= alpha;
      m_i = mnew;
    }
    float sum = 0.f;
#pragma unroll
    for (int r = 0; r < 16; r++) {
      float p0 = exp2f(s0[r] - m_i), p1 = exp2f(s1[r] - m_i);
      s0[r] = p0; s1[r] = p1;
      sum += p0 + p1;
    }
    sum += __shfl_xor(sum, 32);
    l_i += sum;

    // ---- pack P -> bf16 B-frags; half-exchange via shfl_xor(32) ----------
    uint P32[2][4][2];
#pragma unroll
    for (int hh = 0; hh < 4; hh++) {
      union { bf16 e[2]; uint u; } w0, w1, w2, w3;
      w0.e[0] = (bf16)s0[(hh << 2) + 0]; w0.e[1] = (bf16)s0[(hh << 2) + 1];
      w1.e[0] = (bf16)s0[(hh << 2) + 2]; w1.e[1] = (bf16)s0[(hh << 2) + 3];
      w2.e[0] = (bf16)s1[(hh << 2) + 0]; w2.e[1] = (bf16)s1[(hh << 2) + 1];
      w3.e[0] = (bf16)s1[(hh << 2) + 2]; w3.e[1] = (bf16)s1[(hh << 2) + 3];
      P32[0][hh][0] = w0.u; P32[0][hh][1] = w1.u;
      P32[1][hh][0] = w2.u; P32[1][hh][1] = w3.u;
    }
    bf16x8 bp[4];
#pragma unroll
    for (int c = 0; c < 4; c++) {
      const int t = c >> 1, sb = c & 1;
      uint send0 = hi ? P32[t][(sb << 1)][0] : P32[t][(sb << 1) + 1][0];
      uint send1 = hi ? P32[t][(sb << 1)][1] : P32[t][(sb << 1) + 1][1];
      uint r0 = __shfl_xor(send0, 32);
      uint r1 = __shfl_xor(send1, 32);
      union { uint u[4]; bf16x8 v; } f;
      if (hi == 0) {
        f.u[0] = P32[t][(sb << 1)][0]; f.u[1] = P32[t][(sb << 1)][1];
        f.u[2] = r0;                   f.u[3] = r1;
      } else {
        f.u[0] = r0;                         f.u[1] = r1;
        f.u[2] = P32[t][(sb << 1) + 1][0];   f.u[3] = P32[t][(sb << 1) + 1][1];
      }
      bp[c] = f.v;
    }

    // ---- O^T += V^T @ P^T : A = V^T frags from LDS, B = bp (in-reg) ------
    __builtin_amdgcn_s_setprio(1);
#pragma unroll
    for (int c = 0; c < 4; c++) {
      const int gsw = (((c << 1) + hi) ^ (l32 & 7)) << 3;
#pragma unroll
      for (int g = 0; g < 4; g++) {
        bf16x8 av = *(const bf16x8*)&Vt[(((g << 5) + l32) << 6) + gsw];
        acc[g] = __builtin_amdgcn_mfma_f32_32x32x16_bf16(av, bp[c], acc[g], 0, 0, 0);
      }
    }
    __builtin_amdgcn_s_setprio(0);
  }

  // ---- epilogue: lane owns q-col l32; dv = g*32 + 8t + 4*hi + r ----------
  const float invl = 1.0f / l_i;
  const int tok = (b << 10) + Q0w + l32;
  bf16* obase = out + ((size_t)tok * HH + h) * DV + hi4;
#pragma unroll
  for (int g = 0; g < 4; g++)
#pragma unroll
    for (int t = 0; t < 4; t++) {
      union { bf16 h4[4]; uint2 u; } pk;
#pragma unroll
      for (int r = 0; r < 4; r++)
        pk.h4[r] = (bf16)(acc[g][(t << 2) + r] * invl);
      *(uint2*)(obase + (g << 5) + (t << 3)) = pk.u;
    }
}

// ---------------- launch ----------------
extern "C" void kernel_launch(void* const* d_in, const int* in_sizes, int n_in,
                              void* d_out, int out_size, void* d_ws, size_t ws_size,
                              hipStream_t stream) {
  (void)in_sizes; (void)n_in; (void)out_size; (void)ws_size;
  const float* x        = (const float*)d_in[0];
  const float* wq_a     = (const float*)d_in[1];
  const float* w_qa_ln  = (const float*)d_in[2];
  const float* wq_b     = (const float*)d_in[3];
  const float* wkv_a    = (const float*)d_in[4];
  const float* w_kva_ln = (const float*)d_in[5];
  const float* wk_b     = (const float*)d_in[6];
  const float* wv_b     = (const float*)d_in[7];
  const float* wo       = (const float*)d_in[8];
  const float* rsin     = (const float*)d_in[9];
  const float* rcos     = (const float*)d_in[10];
  float* out = (float*)d_out;

  // workspace (liveness-aliased), total ~112.2 MB
  char* ws = (char*)d_ws;
  bf16* xb    = (bf16*)(ws + 0);
  bf16* attnb = (bf16*)(ws + 0);
  bf16* xout  = (bf16*)(ws + 16777216);
  bf16* knope = (bf16*)(ws + 16777216);
  bf16* q     = (bf16*)(ws + 34603008);
  bf16* qln   = (bf16*)(ws + 59768832);
  bf16* vT    = (bf16*)(ws + 59768832);
  bf16* wA    = (bf16*)(ws + 76546048);
  bf16* wqbb  = (bf16*)(ws + 85458944);
  bf16* wkvB  = (bf16*)(ws + 94896128);
  bf16* wob   = (bf16*)(ws + 99090432);
  bf16* ckv   = (bf16*)(ws + 107479040);
  bf16* kpe   = (bf16*)(ws + 111673344);

  const float SCALEQ = (1.0f / sqrtf(192.0f)) * 1.44269504088896f;

  dim3 blk(256);
  cvt_all<<<23296, blk, 0, stream>>>(x, wq_a, wkv_a, wq_b, wk_b, wv_b, wo,
                                     xb, wA, wqbb, wkvB, wob, SCALEQ);
  // xout = xb @ [wq_a ; wkv_a]^T
  gemm_bt_bf16<bf16, 0><<<dim3(32, 17), blk, 0, stream>>>(
      xb, wA, xout, nullptr, NTOK, XOUTW, HID, nullptr, nullptr);
  // rmsnorm(q), rmsnorm(kv), rope_k in one dispatch
  norm_rope<<<8704, blk, 0, stream>>>(xout, w_qa_ln, w_kva_ln, qln, ckv, kpe,
                                      rsin, rcos);
  // q = qln @ wq_b^T (pre-scaled by SCALEQ*log2e) with FUSED in-epilogue rope
  gemm_bt_bf16<bf16, 2><<<dim3(32, 24), blk, 0, stream>>>(
      qln, wqbb, q, nullptr, NTOK, HH * DQK, QLR, rsin, rcos);
  // [knope | vT] = ckv @ [wk_b ; wv_b]^T (dual epilogue)
  gemm_bt_bf16<bf16, 1><<<dim3(32, 32), blk, 0, stream>>>(
      ckv, wkvB, knope, vT, NTOK, 4096, KVLR, nullptr, nullptr);
  attn_kernel<<<dim3(256), dim3(512), 0, stream>>>(
      q, knope, kpe, vT, attnb);
  gemm_bt_bf16<float, 0><<<dim3(32, 16), blk, 0, stream>>>(
      attnb, wob, out, nullptr, NTOK, HID, HID, nullptr, nullptr);
}

// Round 12
// 392.205 us; speedup vs baseline: 1.0064x; 1.0064x over previous
//
#include <hip/hip_runtime.h>
#include <stdint.h>

typedef __bf16 bf16;
typedef __bf16 bf16x8 __attribute__((ext_vector_type(8)));
typedef float floatx4 __attribute__((ext_vector_type(4)));
typedef float floatx16 __attribute__((ext_vector_type(16)));

#define HH     16
#define DNOPE  128
#define DROPE  64
#define DV     128
#define DQK    192
#define HID    2048
#define QLR    1536
#define KVLR   512
#define BB     4
#define SS     1024
#define NTOK   4096
#define XOUTW  2176
#define EPSF   1e-6f

// ---------------- helpers ----------------
__device__ inline void cvt_store4(bf16* dst, float a, float b, float c, float d) {
  union { bf16 h[4]; uint2 u; } t;
  t.h[0] = (bf16)a; t.h[1] = (bf16)b; t.h[2] = (bf16)c; t.h[3] = (bf16)d;
  *(uint2*)dst = t.u;
}

__device__ inline void gl_lds16(const bf16* g, bf16* l) {
  __builtin_amdgcn_global_load_lds(
      (const __attribute__((address_space(1))) void*)g,
      (__attribute__((address_space(3))) void*)l, 16, 0, 0);
}

// ---------------- merged fp32 -> bf16 conversion (all weights + x) --------
__global__ __launch_bounds__(256) void cvt_all(
    const float* __restrict__ x, const float* __restrict__ wq_a,
    const float* __restrict__ wkv_a, const float* __restrict__ wq_b,
    const float* __restrict__ wk_b, const float* __restrict__ wv_b,
    const float* __restrict__ wo, bf16* __restrict__ xb,
    bf16* __restrict__ wA, bf16* __restrict__ wqbb,
    bf16* __restrict__ wkvB, bf16* __restrict__ wob, float scaleq) {
  const int blk = blockIdx.x, tid = threadIdx.x;
  const float* s; bf16* d; int rel; float sc = 1.0f;
  if (blk < 8192)       { rel = blk;         s = x;    d = xb; }
  else if (blk < 11264) { rel = blk - 8192;  s = wq_a; d = wA; }
  else if (blk < 12544) { // wkv_a pad to 640 rows
    rel = blk - 11264;
    int i = (rel * 256 + tid) << 2;
    bf16* dd = wA + 3145728;
    if ((i >> 11) < 576) {
      float4 v = *(const float4*)(wkv_a + i);
      cvt_store4(dd + i, v.x, v.y, v.z, v.w);
    } else {
      *(uint2*)(dd + i) = make_uint2(0u, 0u);
    }
    return;
  }
  else if (blk < 17152) { rel = blk - 12544; s = wq_b; d = wqbb; sc = scaleq; }
  else if (blk < 18176) { rel = blk - 17152; s = wk_b; d = wkvB; }
  else if (blk < 19200) { rel = blk - 18176; s = wv_b; d = wkvB + 1048576; }
  else                  { rel = blk - 19200; s = wo;   d = wob; }
  int i = (rel * 256 + tid) << 2;
  float4 v = *(const float4*)(s + i);
  cvt_store4(d + i, v.x * sc, v.y * sc, v.z * sc, v.w * sc);
}

// ---------------- GEMM: C[M,N] = A[M,K] @ Bw[N,K]^T (all bf16 in) ----------
// Proven R6/R8 config: 128^2 tile, BK=32, THREE 16KB stages (48KB LDS ->
// 3 blocks/CU), counted depth-2 pipeline (wait vmcnt(4); barrier; issue
// k+2; compute k), T2 swizzle (pre-swizzled global source + XOR'd read),
// XCD block swizzle. ~620-660 TF -- at the counted-2-phase ceiling.
// EPI: 0 = plain store, 1 = dual knope/vT epilogue, 2 = fused rope-q.
template <typename TC, int EPI>
__global__ __launch_bounds__(256) void gemm_bt_bf16(
    const bf16* __restrict__ A, const bf16* __restrict__ Bw,
    TC* __restrict__ C0, bf16* __restrict__ C1, int M, int N, int K,
    const float* __restrict__ rs, const float* __restrict__ rc) {
  __shared__ __align__(16) bf16 As[3][128 * 32];
  __shared__ __align__(16) bf16 Bs[3][128 * 32];
  const int tid  = threadIdx.x;
  const int wave = tid >> 6, lane = tid & 63;
  const int gx = gridDim.x;
  const int fid = blockIdx.y * gx + blockIdx.x;
  const int cpx = (gx * gridDim.y) >> 3;
  const int sid = (fid & 7) * cpx + (fid >> 3);
  const int m0 = (sid % gx) << 7, n0 = (sid / gx) << 7;
  const int quad = lane >> 4, l16 = lane & 15;
  const int wm = (wave >> 1) << 6, wn = (wave & 1) << 6;

  const int srow0 = tid >> 2, g = tid & 3;
  const int gsw = g ^ ((srow0 >> 1) & 3);
  const int d0 = srow0 * 32 + (g << 3);
  const int d1 = d0 + 64 * 32;
  const bf16* gA0 = A  + (size_t)(m0 + srow0) * K + (gsw << 3);
  const bf16* gA1 = A  + (size_t)(m0 + srow0 + 64) * K + (gsw << 3);
  const bf16* gB0 = Bw + (size_t)(n0 + srow0) * K + (gsw << 3);
  const bf16* gB1 = Bw + (size_t)(n0 + srow0 + 64) * K + (gsw << 3);

  floatx4 acc[4][4];
#pragma unroll
  for (int i = 0; i < 4; i++)
#pragma unroll
    for (int j = 0; j < 4; j++) acc[i][j] = floatx4{0.f, 0.f, 0.f, 0.f};

  const int nk = K >> 5;
  gl_lds16(gA0, As[0] + d0); gl_lds16(gA1, As[0] + d1);
  gl_lds16(gB0, Bs[0] + d0); gl_lds16(gB1, Bs[0] + d1);
  gl_lds16(gA0 + 32, As[1] + d0); gl_lds16(gA1 + 32, As[1] + d1);
  gl_lds16(gB0 + 32, Bs[1] + d0); gl_lds16(gB1 + 32, Bs[1] + d1);

  const int swr = (l16 >> 1) & 3;
  int cur = 0, nx2 = 2;
  for (int kt = 0; kt < nk; kt++) {
    if (kt + 1 < nk)
      asm volatile("s_waitcnt vmcnt(4)\n\ts_barrier" ::: "memory");
    else
      asm volatile("s_waitcnt vmcnt(0)\n\ts_barrier" ::: "memory");
    if (kt + 2 < nk) {
      const size_t kk = (size_t)(kt + 2) << 5;
      gl_lds16(gA0 + kk, As[nx2] + d0); gl_lds16(gA1 + kk, As[nx2] + d1);
      gl_lds16(gB0 + kk, Bs[nx2] + d0); gl_lds16(gB1 + kk, Bs[nx2] + d1);
    }
    __builtin_amdgcn_sched_barrier(0);   // pin DMA issue before compute

    const bf16* cA = As[cur];
    const bf16* cB = Bs[cur];
    bf16x8 af[4], bv[4];
#pragma unroll
    for (int i = 0; i < 4; i++) {
      const int r = wm + (i << 4) + l16;
      af[i] = *(const bf16x8*)&cA[r * 32 + (((quad ^ swr) & 3) << 3)];
    }
#pragma unroll
    for (int j = 0; j < 4; j++) {
      const int r = wn + (j << 4) + l16;
      bv[j] = *(const bf16x8*)&cB[r * 32 + (((quad ^ swr) & 3) << 3)];
    }
#pragma unroll
    for (int i = 0; i < 4; i++)
#pragma unroll
      for (int j = 0; j < 4; j++)
        acc[i][j] = __builtin_amdgcn_mfma_f32_16x16x32_bf16(af[i], bv[j], acc[i][j], 0, 0, 0);

    cur = (cur == 2) ? 0 : cur + 1;
    nx2 = (nx2 == 2) ? 0 : nx2 + 1;
  }

  if constexpr (EPI == 1) {
    if (n0 >= 2048) {
#pragma unroll
      for (int i = 0; i < 4; i++) {
        int gm = m0 + wm + (i << 4) + (quad << 2);
        int bb = gm >> 10, s = gm & 1023;
#pragma unroll
        for (int j = 0; j < 4; j++) {
          int gn = n0 + wn + (j << 4) + l16 - 2048;
          int hh = gn >> 7, vd = gn & 127;
          union { bf16 h4[4]; uint2 u; } pk;
#pragma unroll
          for (int r = 0; r < 4; r++) pk.h4[r] = (bf16)acc[i][j][r];
          *(uint2*)(C1 + ((((size_t)bb * HH + hh) * DV + vd) << 10) + s) = pk.u;
        }
      }
      return;
    }
  }
  if constexpr (EPI == 2) {
    // fused rope-q: rotate pairs where head-local d = (col%192) in [128,192)
#pragma unroll
    for (int i = 0; i < 4; i++)
#pragma unroll
      for (int j = 0; j < 4; j++) {
        const int cb = (n0 + wn + (j << 4)) % 192;   // j-tile head-local base
        const int gn = n0 + wn + (j << 4) + l16;
        if (cb >= 128) {                              // wave-uniform branch
          const int ir = (cb + l16 - 128) >> 1;       // same for both pair lanes
#pragma unroll
          for (int r = 0; r < 4; r++) {
            int gm = m0 + wm + (i << 4) + (quad << 2) + r;
            int pos = gm & (SS - 1);
            float own  = acc[i][j][r];
            float part = __shfl_xor(own, 1);          // pair partner (lane^1)
            float cth = rc[(pos << 5) + ir], sth = rs[(pos << 5) + ir];
            acc[i][j][r] = (l16 & 1) ? (part * sth + own * cth)   // odd:  o'
                                     : (own * cth - part * sth);  // even: e'
          }
        }
#pragma unroll
        for (int r = 0; r < 4; r++) {
          int gm = m0 + wm + (i << 4) + (quad << 2) + r;
          C0[(size_t)gm * N + gn] = (TC)acc[i][j][r];
        }
      }
    return;
  }
  const int ldc = (EPI == 1) ? 2048 : N;
#pragma unroll
  for (int i = 0; i < 4; i++)
#pragma unroll
    for (int j = 0; j < 4; j++) {
      int gn = n0 + wn + (j << 4) + l16;
#pragma unroll
      for (int r = 0; r < 4; r++) {
        int gm = m0 + wm + (i << 4) + (quad << 2) + r;
        C0[(size_t)gm * ldc + gn] = (TC)acc[i][j][r];
      }
    }
}

// ---------------- fused rmsnorm(q) + rmsnorm(kv) + rope_k ----------------
__global__ __launch_bounds__(256) void norm_rope(
    const bf16* __restrict__ xout, const float* __restrict__ w_qa_ln,
    const float* __restrict__ w_kva_ln, bf16* __restrict__ qln,
    bf16* __restrict__ ckv, bf16* __restrict__ kpe,
    const float* __restrict__ rsin, const float* __restrict__ rcos) {
  const int blk = blockIdx.x, tid = threadIdx.x;
  if (blk < 8192) {
    const int row = blk & 4095;
    const bool isq = blk < 4096;
    const bf16* p = xout + (size_t)row * XOUTW + (isq ? 0 : QLR);
    const float* w = isq ? w_qa_ln : w_kva_ln;
    bf16* o = isq ? (qln + (size_t)row * QLR) : (ckv + (size_t)row * KVLR);
    const int L = isq ? QLR : KVLR;
    float ss = 0.f;
    for (int c = tid << 2; c < L; c += 1024) {
      union { uint2 u; bf16 h[4]; } t;
      t.u = *(const uint2*)(p + c);
#pragma unroll
      for (int r = 0; r < 4; r++) { float v = (float)t.h[r]; ss += v * v; }
    }
#pragma unroll
    for (int off = 32; off > 0; off >>= 1) ss += __shfl_down(ss, off);
    __shared__ float red[4];
    if ((tid & 63) == 0) red[tid >> 6] = ss;
    __syncthreads();
    float rs = rsqrtf((red[0] + red[1] + red[2] + red[3]) / (float)L + EPSF);
    for (int c = tid << 2; c < L; c += 1024) {
      union { uint2 u; bf16 h[4]; } t, ot;
      t.u = *(const uint2*)(p + c);
#pragma unroll
      for (int r = 0; r < 4; r++) ot.h[r] = (bf16)((float)t.h[r] * rs * w[c + r]);
      *(uint2*)(o + c) = ot.u;
    }
  } else {
    int idx = (blk - 8192) * 256 + tid;   // NTOK*32
    int i = idx & 31, row = idx >> 5;
    int pos = row & (SS - 1);
    union { uint u; bf16 h2[2]; } t;
    t.u = *(const uint*)(xout + (size_t)row * XOUTW + QLR + KVLR + (i << 1));
    float e = (float)t.h2[0], o = (float)t.h2[1];
    float c = rcos[(pos << 5) + i], s = rsin[(pos << 5) + i];
    t.h2[0] = (bf16)(e * c - o * s);
    t.h2[1] = (bf16)(e * s + o * c);
    *(uint*)(kpe + (size_t)row * DROPE + (i << 1)) = t.u;
  }
}

// ---------------- flash attention: paired q-128 tiles, balanced blocks -----
// R8 body + R11 XCD-grouped mapping + R12: THREE KV buffers with counted
// depth-2 prefetch (the same discipline that fixed the GEMMs in R6).
// R11's null showed attn is drain-latency bound: the depth-1 dbuf paid the
// residual of a DMA issued only one compute-phase earlier at EVERY slot's
// vmcnt(0). Now: prologue loads Q (12 loads) then issues slots 0,1 (5 each);
// top of slot s waits vmcnt(5) (slot s drained, slot s+1's 5 in flight),
// barrier, issues slot s+2 into buf[(s+2)%3] -> each slot gets TWO full
// slot-times of flight; the top-of-slot wait pays ~0. Buffer-reuse hazard:
// the barrier at slot-s top orders all waves past slot s-1's compute before
// s+2 overwrites buf[(s-1)%3] (same argument as the GEMM 3-stage). LDS
// 120KB -- was 1 block/CU at 80KB anyway, occupancy unchanged.
__global__ __launch_bounds__(512, 2) void attn_kernel(
    const bf16* __restrict__ q, const bf16* __restrict__ knope,
    const bf16* __restrict__ kpe, const bf16* __restrict__ vT,
    bf16* __restrict__ out) {
  const int p = blockIdx.x;
  const int logical = ((p & 7) << 5) + (p >> 3);
  const int bt = logical & 3;          // 0..3 -> tile pair {bt, 7-bt}
  const int h = (logical >> 2) & 15, b = logical >> 6;
  const int nkt = (8 - bt) << 1;       // slots for the longer tile
  // 3 buffers x 20480 elems: Kn [0,8192) Kp [8192,12288) Vt [12288,20480)
  __shared__ __align__(16) bf16 smem[61440];
  const int tid = threadIdx.x, wave = tid >> 6, lane = tid & 63;
  const int l32 = lane & 31, hi = lane >> 5;
  const int hi4 = hi << 2;
  const int tile = (wave < 4) ? bt : (7 - bt);
  const int Q0w = (tile << 7) + ((wave & 3) << 5);  // this wave's first q row
  const int qg = Q0w + l32;            // this lane's q row (col of S^T)

  // ---- per-lane global staging addresses (slot 0), swizzle inverse map ----
  const bf16 *gkn0, *gkn1, *gkp, *gvt0, *gvt1;
  {
    int c = wave << 1;
    int r = (c << 2) + (lane >> 4);
    int bi = (lane & 15) ^ (r & 15);
    gkn0 = knope + ((size_t)((b << 10) + r) * HH + h) * DNOPE + (bi << 3);
    r = ((c + 1) << 2) + (lane >> 4);
    bi = (lane & 15) ^ (r & 15);
    gkn1 = knope + ((size_t)((b << 10) + r) * HH + h) * DNOPE + (bi << 3);
    r = (wave << 3) + (lane >> 3);
    bi = (lane & 7) ^ (r & 7);
    gkp = kpe + (size_t)((b << 10) + r) * DROPE + (bi << 3);
    int dv = (wave << 4) + (lane >> 3);
    bi = (lane & 7) ^ (dv & 7);
    gvt0 = vT + ((((size_t)b * HH + h) * DV + dv) << 10) + (bi << 3);
    dv += 8;
    bi = (lane & 7) ^ (dv & 7);
    gvt1 = vT + ((((size_t)b * HH + h) * DV + dv) << 10) + (bi << 3);
  }
  const size_t knstep = (size_t)64 * HH * DNOPE;
  const size_t kpstep = (size_t)64 * DROPE;
  const int woff = wave << 10, woff2 = wave << 9;

  // ---- Q B-frags FIRST (oldest vmem -> drained by the first vmcnt(5)) ----
  bf16x8 qb[12];
  {
    const bf16* qbase =
        q + ((size_t)((b << 10) + Q0w + l32) * HH + h) * DQK + (hi << 3);
#pragma unroll
    for (int dc = 0; dc < 12; dc++)
      qb[dc] = *(const bf16x8*)(qbase + (dc << 4));
  }

  // prologue: issue slot 0 -> buf0, slot 1 -> buf1 (5 loads/wave each)
#pragma unroll
  for (int s0i = 0; s0i < 2; s0i++) {
    bf16* bufp = smem + s0i * 20480;
    gl_lds16(gkn0, bufp + woff);
    gl_lds16(gkn1, bufp + woff + 512);
    gl_lds16(gkp,  bufp + 8192 + woff2);
    gl_lds16(gvt0, bufp + 12288 + woff);
    gl_lds16(gvt1, bufp + 12288 + woff + 512);
    gkn0 += knstep; gkn1 += knstep; gkp += kpstep; gvt0 += 64; gvt1 += 64;
  }

  floatx16 acc[4];
#pragma unroll
  for (int g = 0; g < 4; g++)
#pragma unroll
    for (int r = 0; r < 16; r++) acc[g][r] = 0.f;
  float m_i = -1e30f, l_i = 0.f;

  int cur = 0, nx2 = 2;                // s % 3, (s+2) % 3
  for (int s = 0; s < nkt; s++) {
    const int k0 = s << 6;
    // slot s (and Q at s=0) drained; slot s+1's 5 loads stay in flight.
    if (s + 1 < nkt)
      asm volatile("s_waitcnt vmcnt(5)\n\ts_barrier" ::: "memory");
    else
      asm volatile("s_waitcnt vmcnt(0)\n\ts_barrier" ::: "memory");
    if (s + 2 < nkt) {   // issue slot s+2 (buf[(s+2)%3] held slot s-1: done)
      bf16* bufp = smem + nx2 * 20480;
      gl_lds16(gkn0, bufp + woff);
      gl_lds16(gkn1, bufp + woff + 512);
      gl_lds16(gkp,  bufp + 8192 + woff2);
      gl_lds16(gvt0, bufp + 12288 + woff);
      gl_lds16(gvt1, bufp + 12288 + woff + 512);
      gkn0 += knstep; gkn1 += knstep; gkp += kpstep; gvt0 += 64; gvt1 += 64;
    }
    __builtin_amdgcn_sched_barrier(0);   // pin DMA issue before compute
    const bf16* Kn = smem + cur * 20480;
    cur = (cur == 2) ? 0 : cur + 1;
    nx2 = (nx2 == 2) ? 0 : nx2 + 1;
    if (k0 > Q0w + 31) continue;         // fully masked for this wave: skip

    const bf16* Kp = Kn + 8192;
    const bf16* Vt = Kn + 12288;

    // ---- S^T = K @ Q^T : two 32x32 tiles (k-rows 0..31, 32..63) ----------
    floatx16 s0, s1;
#pragma unroll
    for (int r = 0; r < 16; r++) { s0[r] = 0.f; s1[r] = 0.f; }
    __builtin_amdgcn_s_setprio(1);
#pragma unroll
    for (int dc = 0; dc < 12; dc++) {
      bf16x8 ak0, ak1;
      if (dc < 8) {
        int gi = (((dc << 1) + hi) ^ (l32 & 15)) << 3;
        ak0 = *(const bf16x8*)&Kn[(l32 << 7) + gi];
        ak1 = *(const bf16x8*)&Kn[((32 + l32) << 7) + gi];
      } else {
        int gi = ((((dc - 8) << 1) + hi) ^ (l32 & 7)) << 3;
        ak0 = *(const bf16x8*)&Kp[(l32 << 6) + gi];
        ak1 = *(const bf16x8*)&Kp[((32 + l32) << 6) + gi];
      }
      s0 = __builtin_amdgcn_mfma_f32_32x32x16_bf16(ak0, qb[dc], s0, 0, 0, 0);
      s1 = __builtin_amdgcn_mfma_f32_32x32x16_bf16(ak1, qb[dc], s1, 0, 0, 0);
    }
    __builtin_amdgcn_s_setprio(0);

    // ---- causal mask (diagonal-region slots only, wave-uniform branch) ---
    if (k0 + 63 > Q0w) {
#pragma unroll
      for (int r = 0; r < 16; r++) {
        int rp = (r & 3) + ((r >> 2) << 3) + hi4;   // k row within tile
        if (k0 + rp > qg)      s0[r] = -1e30f;
        if (k0 + 32 + rp > qg) s1[r] = -1e30f;
      }
    }

    // ---- online softmax, fully in-register (lane owns q-col) -------------
    float mx = -1e30f;
#pragma unroll
    for (int r = 0; r < 16; r++) mx = fmaxf(mx, fmaxf(s0[r], s1[r]));
    mx = fmaxf(mx, __shfl_xor(mx, 32));   // lanes l,l^32 share the q-col
    if (!__all(mx - m_i <= 8.0f)) {       // defer-max (T13, THR=8)
      float mnew = fmaxf(m_i, mx);
      float alpha = exp2f(m_i - mnew);
      l_i *= alpha;
#pragma unroll
      for (int g = 0; g < 4; g++)
#pragma unroll
        for (int r = 0; r < 16; r++) acc[g][r] *= alpha;
      m_i = mnew;
    }
    float sum = 0.f;
#pragma unroll
    for (int r = 0; r < 16; r++) {
      float p0 = exp2f(s0[r] - m_i), p1 = exp2f(s1[r] - m_i);
      s0[r] = p0; s1[r] = p1;
      sum += p0 + p1;
    }
    sum += __shfl_xor(sum, 32);
    l_i += sum;

    // ---- pack P -> bf16 B-frags; half-exchange via shfl_xor(32) ----------
    uint P32[2][4][2];
#pragma unroll
    for (int hh = 0; hh < 4; hh++) {
      union { bf16 e[2]; uint u; } w0, w1, w2, w3;
      w0.e[0] = (bf16)s0[(hh << 2) + 0]; w0.e[1] = (bf16)s0[(hh << 2) + 1];
      w1.e[0] = (bf16)s0[(hh << 2) + 2]; w1.e[1] = (bf16)s0[(hh << 2) + 3];
      w2.e[0] = (bf16)s1[(hh << 2) + 0]; w2.e[1] = (bf16)s1[(hh << 2) + 1];
      w3.e[0] = (bf16)s1[(hh << 2) + 2]; w3.e[1] = (bf16)s1[(hh << 2) + 3];
      P32[0][hh][0] = w0.u; P32[0][hh][1] = w1.u;
      P32[1][hh][0] = w2.u; P32[1][hh][1] = w3.u;
    }
    bf16x8 bp[4];
#pragma unroll
    for (int c = 0; c < 4; c++) {
      const int t = c >> 1, sb = c & 1;
      uint send0 = hi ? P32[t][(sb << 1)][0] : P32[t][(sb << 1) + 1][0];
      uint send1 = hi ? P32[t][(sb << 1)][1] : P32[t][(sb << 1) + 1][1];
      uint r0 = __shfl_xor(send0, 32);
      uint r1 = __shfl_xor(send1, 32);
      union { uint u[4]; bf16x8 v; } f;
      if (hi == 0) {
        f.u[0] = P32[t][(sb << 1)][0]; f.u[1] = P32[t][(sb << 1)][1];
        f.u[2] = r0;                   f.u[3] = r1;
      } else {
        f.u[0] = r0;                         f.u[1] = r1;
        f.u[2] = P32[t][(sb << 1) + 1][0];   f.u[3] = P32[t][(sb << 1) + 1][1];
      }
      bp[c] = f.v;
    }

    // ---- O^T += V^T @ P^T : A = V^T frags from LDS, B = bp (in-reg) ------
    __builtin_amdgcn_s_setprio(1);
#pragma unroll
    for (int c = 0; c < 4; c++) {
      const int gsw = (((c << 1) + hi) ^ (l32 & 7)) << 3;
#pragma unroll
      for (int g = 0; g < 4; g++) {
        bf16x8 av = *(const bf16x8*)&Vt[(((g << 5) + l32) << 6) + gsw];
        acc[g] = __builtin_amdgcn_mfma_f32_32x32x16_bf16(av, bp[c], acc[g], 0, 0, 0);
      }
    }
    __builtin_amdgcn_s_setprio(0);
  }

  // ---- epilogue: lane owns q-col l32; dv = g*32 + 8t + 4*hi + r ----------
  const float invl = 1.0f / l_i;
  const int tok = (b << 10) + Q0w + l32;
  bf16* obase = out + ((size_t)tok * HH + h) * DV + hi4;
#pragma unroll
  for (int g = 0; g < 4; g++)
#pragma unroll
    for (int t = 0; t < 4; t++) {
      union { bf16 h4[4]; uint2 u; } pk;
#pragma unroll
      for (int r = 0; r < 4; r++)
        pk.h4[r] = (bf16)(acc[g][(t << 2) + r] * invl);
      *(uint2*)(obase + (g << 5) + (t << 3)) = pk.u;
    }
}

// ---------------- launch ----------------
extern "C" void kernel_launch(void* const* d_in, const int* in_sizes, int n_in,
                              void* d_out, int out_size, void* d_ws, size_t ws_size,
                              hipStream_t stream) {
  (void)in_sizes; (void)n_in; (void)out_size; (void)ws_size;
  const float* x        = (const float*)d_in[0];
  const float* wq_a     = (const float*)d_in[1];
  const float* w_qa_ln  = (const float*)d_in[2];
  const float* wq_b     = (const float*)d_in[3];
  const float* wkv_a    = (const float*)d_in[4];
  const float* w_kva_ln = (const float*)d_in[5];
  const float* wk_b     = (const float*)d_in[6];
  const float* wv_b     = (const float*)d_in[7];
  const float* wo       = (const float*)d_in[8];
  const float* rsin     = (const float*)d_in[9];
  const float* rcos     = (const float*)d_in[10];
  float* out = (float*)d_out;

  // workspace (liveness-aliased), total ~112.2 MB
  char* ws = (char*)d_ws;
  bf16* xb    = (bf16*)(ws + 0);
  bf16* attnb = (bf16*)(ws + 0);
  bf16* xout  = (bf16*)(ws + 16777216);
  bf16* knope = (bf16*)(ws + 16777216);
  bf16* q     = (bf16*)(ws + 34603008);
  bf16* qln   = (bf16*)(ws + 59768832);
  bf16* vT    = (bf16*)(ws + 59768832);
  bf16* wA    = (bf16*)(ws + 76546048);
  bf16* wqbb  = (bf16*)(ws + 85458944);
  bf16* wkvB  = (bf16*)(ws + 94896128);
  bf16* wob   = (bf16*)(ws + 99090432);
  bf16* ckv   = (bf16*)(ws + 107479040);
  bf16* kpe   = (bf16*)(ws + 111673344);

  const float SCALEQ = (1.0f / sqrtf(192.0f)) * 1.44269504088896f;

  dim3 blk(256);
  cvt_all<<<23296, blk, 0, stream>>>(x, wq_a, wkv_a, wq_b, wk_b, wv_b, wo,
                                     xb, wA, wqbb, wkvB, wob, SCALEQ);
  // xout = xb @ [wq_a ; wkv_a]^T
  gemm_bt_bf16<bf16, 0><<<dim3(32, 17), blk, 0, stream>>>(
      xb, wA, xout, nullptr, NTOK, XOUTW, HID, nullptr, nullptr);
  // rmsnorm(q), rmsnorm(kv), rope_k in one dispatch
  norm_rope<<<8704, blk, 0, stream>>>(xout, w_qa_ln, w_kva_ln, qln, ckv, kpe,
                                      rsin, rcos);
  // q = qln @ wq_b^T (pre-scaled by SCALEQ*log2e) with FUSED in-epilogue rope
  gemm_bt_bf16<bf16, 2><<<dim3(32, 24), blk, 0, stream>>>(
      qln, wqbb, q, nullptr, NTOK, HH * DQK, QLR, rsin, rcos);
  // [knope | vT] = ckv @ [wk_b ; wv_b]^T (dual epilogue)
  gemm_bt_bf16<bf16, 1><<<dim3(32, 32), blk, 0, stream>>>(
      ckv, wkvB, knope, vT, NTOK, 4096, KVLR, nullptr, nullptr);
  attn_kernel<<<dim3(256), dim3(512), 0, stream>>>(
      q, knope, kpe, vT, attnb);
  gemm_bt_bf16<float, 0><<<dim3(32, 16), blk, 0, stream>>>(
      attnb, wob, out, nullptr, NTOK, HID, HID, nullptr, nullptr);
}